// Round 14
// baseline (263.445 us; speedup 1.0000x reference)
//
#include <hip/hip_runtime.h>
#include <hip/hip_bf16.h>

#define N_NODES 50000
#define E_EDGES 600000
#define HDIM    128

#define QKV_BLOCKS  ((N_NODES + 63) / 64)     // 782 (64 rows/block, all 3 mats)
#define EDGE_BLOCKS ((E_EDGES + 255) / 256)   // 2344
#define SCAN_BLOCKS ((N_NODES + 255) / 256)   // 196
#define ROW_BLOCKS  (N_NODES / 4)             // 12500 (4 waves/block, 1 wave/row)

typedef float f32x4  __attribute__((ext_vector_type(4)));
typedef short short8 __attribute__((ext_vector_type(8)));

__device__ __forceinline__ unsigned short f2bf(float f) {
    __hip_bfloat16 h = __float2bfloat16(f);
    return *reinterpret_cast<unsigned short*>(&h);
}

// ---- Phase 1 (MFMA): Q,K,V = x W^T + b; x staged ONCE, loop over 3 mats ----
// Split precision: x = xh + xl, W = Wh + Wl (bf16); Y = xh*Wh + xl*Wh + xh*Wl.
// mat loop NOT unrolled (one mat's B-frags live at a time); VGPR capped via
// launch_bounds min-waves=4 -> <=128 VGPR -> 4 blocks/CU.
__global__ __launch_bounds__(256, 4) void qkv_mfma_kernel(
    const float* __restrict__ x,
    const float* __restrict__ Wq, const float* __restrict__ bq,
    const float* __restrict__ Wk, const float* __restrict__ bk,
    const float* __restrict__ Wv, const float* __restrict__ bv,
    float* __restrict__ Q, unsigned short* __restrict__ Kb,
    unsigned short* __restrict__ Vb)
{
    __shared__ __align__(16) unsigned short Ah[64 * HDIM];  // 16 KB
    __shared__ __align__(16) unsigned short Al[64 * HDIM];  // 16 KB
    const int r0 = blockIdx.x * 64;

    // ---- stage x rows 64x128 as bf16 hi/lo, swizzled (once per block) ----
    for (int t = threadIdx.x; t < 2048; t += 256) {
        const int r  = t >> 5;           // 0..63
        const int k4 = t & 31;           // float4 index 0..31
        int gr = r0 + r; if (gr >= N_NODES) gr = N_NODES - 1;
        const float4 xv = *(const float4*)&x[(size_t)gr * HDIM + k4 * 4];
        const unsigned ux = __float_as_uint(xv.x), uy = __float_as_uint(xv.y);
        const unsigned uz = __float_as_uint(xv.z), uw = __float_as_uint(xv.w);
        ushort4 hv, lv;
        hv.x = (unsigned short)(ux >> 16); hv.y = (unsigned short)(uy >> 16);
        hv.z = (unsigned short)(uz >> 16); hv.w = (unsigned short)(uw >> 16);
        lv.x = f2bf(xv.x - __uint_as_float(ux & 0xffff0000u));
        lv.y = f2bf(xv.y - __uint_as_float(uy & 0xffff0000u));
        lv.z = f2bf(xv.z - __uint_as_float(uz & 0xffff0000u));
        lv.w = f2bf(xv.w - __uint_as_float(uw & 0xffff0000u));
        const int byte = (r << 8) + (k4 << 3);
        const int swz  = byte ^ ((r & 7) << 4);
        *(ushort4*)((char*)Ah + swz) = hv;
        *(ushort4*)((char*)Al + swz) = lv;
    }
    __syncthreads();

    const int lane = threadIdx.x & 63;
    const int w    = threadIdx.x >> 6;   // wave 0..3
    const int lrow = lane & 15;
    const int lgrp = lane >> 4;
    const int nb   = w * 32;             // wave's col base within mat

#pragma unroll 1
    for (int mat = 0; mat < 3; ++mat) {
        const float* Wm = (mat == 0) ? Wq : (mat == 1) ? Wk : Wv;
        const float* bm = (mat == 0) ? bq : (mat == 1) ? bk : bv;

        // ---- B fragments: hi/lo, 2 strips x 4 k-steps (one mat at a time) ----
        short8 Bh[2][4], Bl[2][4];
#pragma unroll
        for (int st = 0; st < 2; ++st) {
            const int col = nb + st * 16 + lrow;
#pragma unroll
            for (int ks = 0; ks < 4; ++ks) {
                const int k0 = ks * 32 + lgrp * 8;
                const float* p = Wm + (size_t)col * HDIM + k0;
                const float4 a = *(const float4*)p;
                const float4 b = *(const float4*)(p + 4);
                const float f[8] = {a.x, a.y, a.z, a.w, b.x, b.y, b.z, b.w};
                short8 h, l;
#pragma unroll
                for (int j = 0; j < 8; ++j) {
                    const unsigned u = __float_as_uint(f[j]);
                    h[j] = (short)(u >> 16);
                    l[j] = (short)f2bf(f[j] - __uint_as_float(u & 0xffff0000u));
                }
                Bh[st][ks] = h; Bl[st][ks] = l;
            }
        }
        const float bias0 = bm[nb + lrow];
        const float bias1 = bm[nb + 16 + lrow];

        // ---- compute: 4 M-subtiles of 16 rows ----
#pragma unroll
        for (int s = 0; s < 4; ++s) {
            f32x4 acc0 = {0.f, 0.f, 0.f, 0.f};
            f32x4 acc1 = {0.f, 0.f, 0.f, 0.f};
            const int row = s * 16 + lrow;
#pragma unroll
            for (int ks = 0; ks < 4; ++ks) {
                const int byte = (row << 8) + ((ks * 32 + lgrp * 8) << 1);
                const int swz  = byte ^ ((row & 7) << 4);
                const short8 ah = *(const short8*)((const char*)Ah + swz);
                const short8 al = *(const short8*)((const char*)Al + swz);
                acc0 = __builtin_amdgcn_mfma_f32_16x16x32_bf16(ah, Bh[0][ks], acc0, 0, 0, 0);
                acc0 = __builtin_amdgcn_mfma_f32_16x16x32_bf16(al, Bh[0][ks], acc0, 0, 0, 0);
                acc0 = __builtin_amdgcn_mfma_f32_16x16x32_bf16(ah, Bl[0][ks], acc0, 0, 0, 0);
                acc1 = __builtin_amdgcn_mfma_f32_16x16x32_bf16(ah, Bh[1][ks], acc1, 0, 0, 0);
                acc1 = __builtin_amdgcn_mfma_f32_16x16x32_bf16(al, Bh[1][ks], acc1, 0, 0, 0);
                acc1 = __builtin_amdgcn_mfma_f32_16x16x32_bf16(ah, Bl[1][ks], acc1, 0, 0, 0);
            }
            const int orow0 = r0 + s * 16 + lgrp * 4;
            if (mat == 0) {
#pragma unroll
                for (int i = 0; i < 4; ++i) {
                    const int row_o = orow0 + i;
                    if (row_o < N_NODES) {
                        Q[(size_t)row_o * HDIM + nb + lrow]      = acc0[i] + bias0;
                        Q[(size_t)row_o * HDIM + nb + 16 + lrow] = acc1[i] + bias1;
                    }
                }
            } else {
                unsigned short* dst = (mat == 1) ? Kb : Vb;
#pragma unroll
                for (int i = 0; i < 4; ++i) {
                    const int row_o = orow0 + i;
                    if (row_o < N_NODES) {
                        dst[(size_t)row_o * HDIM + nb + lrow]      = f2bf(acc0[i] + bias0);
                        dst[(size_t)row_o * HDIM + nb + 16 + lrow] = f2bf(acc1[i] + bias1);
                    }
                }
            }
        }
    }
}

// ---- Phase 2a: histogram of destination rows ----
__global__ __launch_bounds__(256) void hist_kernel(
    const int* __restrict__ ei, int* __restrict__ counts)
{
    const int e = blockIdx.x * 256 + threadIdx.x;
    if (e < E_EDGES) atomicAdd(&counts[ei[e]], 1);
}

// ---- Phase 2b: exclusive prefix scan (3 small kernels) ----
__global__ __launch_bounds__(256) void scan_partial_kernel(
    const int* __restrict__ counts, int* __restrict__ offs, int* __restrict__ aux)
{
    __shared__ int s[256];
    const int i = blockIdx.x * 256 + threadIdx.x;
    const int v = (i < N_NODES) ? counts[i] : 0;
    s[threadIdx.x] = v;
    __syncthreads();
    for (int d = 1; d < 256; d <<= 1) {
        int t = (threadIdx.x >= d) ? s[threadIdx.x - d] : 0;
        __syncthreads();
        s[threadIdx.x] += t;
        __syncthreads();
    }
    if (i < N_NODES) offs[i] = s[threadIdx.x] - v;   // exclusive within block
    if (threadIdx.x == 255) aux[blockIdx.x] = s[255];
}

__global__ __launch_bounds__(256) void scan_aux_kernel(int* __restrict__ aux)
{
    __shared__ int s[256];
    const int i = threadIdx.x;
    const int v = (i < SCAN_BLOCKS) ? aux[i] : 0;
    s[i] = v;
    __syncthreads();
    for (int d = 1; d < 256; d <<= 1) {
        int t = (i >= d) ? s[i - d] : 0;
        __syncthreads();
        s[i] += t;
        __syncthreads();
    }
    if (i < SCAN_BLOCKS) aux[i] = s[i] - v;          // exclusive
}

__global__ __launch_bounds__(256) void scan_add_kernel(
    int* __restrict__ offs, const int* __restrict__ aux, int* __restrict__ cursor)
{
    const int i = blockIdx.x * 256 + threadIdx.x;
    if (i < N_NODES) {
        const int o = offs[i] + aux[blockIdx.x];
        offs[i] = o;
        cursor[i] = o;
    }
}

// ---- Phase 2c: bin edges by destination row; ONE 8B record per edge ----
__global__ __launch_bounds__(256) void bin_kernel(
    const int* __restrict__ ei, const float* __restrict__ ew,
    int* __restrict__ cursor, uint2* __restrict__ erec)
{
    const int e = blockIdx.x * 256 + threadIdx.x;
    if (e >= E_EDGES) return;
    const int row = ei[e];
    const int pos = atomicAdd(&cursor[row], 1);
    erec[pos] = make_uint2((unsigned)ei[E_EDGES + e], __float_as_uint(ew[e]));
}

// ---- Phase 3: energy; 8 edges/wave in flight; per-block max array ----
__global__ __launch_bounds__(256) void energy_kernel(
    const float* __restrict__ Q, const unsigned short* __restrict__ Kb,
    const int* __restrict__ offs, const int* __restrict__ counts,
    uint2* __restrict__ erec, float* __restrict__ blockmax)
{
    const int row  = (blockIdx.x * 256 + threadIdx.x) >> 6;
    const int lane = threadIdx.x & 63;
    const int eg   = lane >> 4;     // edge group 0..3
    const int sl   = lane & 15;     // sub-lane in group
    const int start = offs[row], len = counts[row];
    const float4 q0 = *(const float4*)&Q[(size_t)row * HDIM + sl * 8];
    const float4 q1 = *(const float4*)&Q[(size_t)row * HDIM + sl * 8 + 4];
    const uint4* kb128 = (const uint4*)Kb;   // one row = 16 uint4
    const float inv_scale = 0.08838834764831845f;  // 1/sqrt(128)
    float lmax = -3.4e38f;
    for (int j0 = 0; j0 < len; j0 += 8) {
        const int  jA = j0 + eg,      jB = j0 + 4 + eg;
        const bool vA = jA < len,     vB = jB < len;
        const int  eA = start + (vA ? jA : 0);
        const int  eB = start + (vB ? jB : 0);
        const uint2 rA = erec[eA];
        const uint2 rB = erec[eB];
        const uint4 uA = kb128[(size_t)rA.x * 16 + sl];
        const uint4 uB = kb128[(size_t)rB.x * 16 + sl];
        float dA = q0.x * __uint_as_float(uA.x << 16)
                 + q0.y * __uint_as_float(uA.x & 0xffff0000u)
                 + q0.z * __uint_as_float(uA.y << 16)
                 + q0.w * __uint_as_float(uA.y & 0xffff0000u)
                 + q1.x * __uint_as_float(uA.z << 16)
                 + q1.y * __uint_as_float(uA.z & 0xffff0000u)
                 + q1.z * __uint_as_float(uA.w << 16)
                 + q1.w * __uint_as_float(uA.w & 0xffff0000u);
        float dB = q0.x * __uint_as_float(uB.x << 16)
                 + q0.y * __uint_as_float(uB.x & 0xffff0000u)
                 + q0.z * __uint_as_float(uB.y << 16)
                 + q0.w * __uint_as_float(uB.y & 0xffff0000u)
                 + q1.x * __uint_as_float(uB.z << 16)
                 + q1.y * __uint_as_float(uB.z & 0xffff0000u)
                 + q1.z * __uint_as_float(uB.w << 16)
                 + q1.w * __uint_as_float(uB.w & 0xffff0000u);
#pragma unroll
        for (int m = 8; m >= 1; m >>= 1) {
            dA += __shfl_xor(dA, m);
            dB += __shfl_xor(dB, m);
        }
        const float enA = dA * inv_scale * __uint_as_float(rA.y);
        const float enB = dB * inv_scale * __uint_as_float(rB.y);
        if (vA) {
            lmax = fmaxf(lmax, enA);
            if (sl == 0) ((float*)erec)[2 * eA + 1] = enA;
        }
        if (vB) {
            lmax = fmaxf(lmax, enB);
            if (sl == 0) ((float*)erec)[2 * eB + 1] = enB;
        }
    }
#pragma unroll
    for (int m = 32; m >= 1; m >>= 1) lmax = fmaxf(lmax, __shfl_xor(lmax, m));
    __shared__ float sm[4];
    if (lane == 0) sm[threadIdx.x >> 6] = lmax;
    __syncthreads();
    if (threadIdx.x == 0)
        blockmax[blockIdx.x] = fmaxf(fmaxf(sm[0], sm[1]), fmaxf(sm[2], sm[3]));
}

__global__ __launch_bounds__(256) void reduce_max_kernel(
    const float* __restrict__ bm, int n, float* __restrict__ gmax)
{
    float m = -3.4e38f;
    for (int i = threadIdx.x; i < n; i += 256) m = fmaxf(m, bm[i]);
#pragma unroll
    for (int s = 32; s >= 1; s >>= 1) m = fmaxf(m, __shfl_xor(m, s));
    __shared__ float sm[4];
    if ((threadIdx.x & 63) == 0) sm[threadIdx.x >> 6] = m;
    __syncthreads();
    if (threadIdx.x == 0) *gmax = fmaxf(fmaxf(sm[0], sm[1]), fmaxf(sm[2], sm[3]));
}

// ---- Phase 4: erec.y = exp(erec.y - max); per-block sum array ----
__global__ __launch_bounds__(256) void expsum_kernel(
    uint2* __restrict__ erec, const float* __restrict__ gmax,
    float* __restrict__ blocksum)
{
    const float m = *gmax;
    const int e = blockIdx.x * 256 + threadIdx.x;
    float p = 0.f;
    if (e < E_EDGES) {
        const uint2 r = erec[e];
        p = __expf(__uint_as_float(r.y) - m);
        erec[e] = make_uint2(r.x, __float_as_uint(p));
    }
#pragma unroll
    for (int s = 32; s >= 1; s >>= 1) p += __shfl_xor(p, s);
    __shared__ float sm[4];
    if ((threadIdx.x & 63) == 0) sm[threadIdx.x >> 6] = p;
    __syncthreads();
    if (threadIdx.x == 0) blocksum[blockIdx.x] = sm[0] + sm[1] + sm[2] + sm[3];
}

__global__ __launch_bounds__(256) void reduce_sum_kernel(
    const float* __restrict__ bs, int n, float* __restrict__ gsum)
{
    float v = 0.f;
    for (int i = threadIdx.x; i < n; i += 256) v += bs[i];
#pragma unroll
    for (int s = 32; s >= 1; s >>= 1) v += __shfl_xor(v, s);
    __shared__ float sm[4];
    if ((threadIdx.x & 63) == 0) sm[threadIdx.x >> 6] = v;
    __syncthreads();
    if (threadIdx.x == 0) *gsum = sm[0] + sm[1] + sm[2] + sm[3];
}

// ---- Phase 5: out[row] = sum_j V[col_j] * p_j / gsum; 8 edges in flight ----
__global__ __launch_bounds__(256) void accum_kernel(
    const unsigned short* __restrict__ Vb,
    const int* __restrict__ offs, const int* __restrict__ counts,
    const uint2* __restrict__ erec, const float* __restrict__ gsum,
    float* __restrict__ out)
{
    const int row  = (blockIdx.x * 256 + threadIdx.x) >> 6;
    const int lane = threadIdx.x & 63;
    const int eg   = lane >> 4;     // edge group 0..3
    const int sl   = lane & 15;     // sub-lane: dims sl*8..sl*8+7
    const float inv = 1.0f / *gsum;
    const int start = offs[row], len = counts[row];
    const uint4* vb128 = (const uint4*)Vb;   // one row = 16 uint4
    float aA[8] = {0.f, 0.f, 0.f, 0.f, 0.f, 0.f, 0.f, 0.f};
    float aB[8] = {0.f, 0.f, 0.f, 0.f, 0.f, 0.f, 0.f, 0.f};
    for (int j0 = 0; j0 < len; j0 += 8) {
        const int  jA = j0 + eg,      jB = j0 + 4 + eg;
        const bool vA = jA < len,     vB = jB < len;
        const int  eA = start + (vA ? jA : 0);
        const int  eB = start + (vB ? jB : 0);
        const uint2 rA = erec[eA];
        const uint2 rB = erec[eB];
        const float wA = vA ? __uint_as_float(rA.y) * inv : 0.f;
        const float wB = vB ? __uint_as_float(rB.y) * inv : 0.f;
        const uint4 uA = vb128[(size_t)rA.x * 16 + sl];
        const uint4 uB = vb128[(size_t)rB.x * 16 + sl];
        aA[0] += __uint_as_float(uA.x << 16) * wA;
        aA[1] += __uint_as_float(uA.x & 0xffff0000u) * wA;
        aA[2] += __uint_as_float(uA.y << 16) * wA;
        aA[3] += __uint_as_float(uA.y & 0xffff0000u) * wA;
        aA[4] += __uint_as_float(uA.z << 16) * wA;
        aA[5] += __uint_as_float(uA.z & 0xffff0000u) * wA;
        aA[6] += __uint_as_float(uA.w << 16) * wA;
        aA[7] += __uint_as_float(uA.w & 0xffff0000u) * wA;
        aB[0] += __uint_as_float(uB.x << 16) * wB;
        aB[1] += __uint_as_float(uB.x & 0xffff0000u) * wB;
        aB[2] += __uint_as_float(uB.y << 16) * wB;
        aB[3] += __uint_as_float(uB.y & 0xffff0000u) * wB;
        aB[4] += __uint_as_float(uB.z << 16) * wB;
        aB[5] += __uint_as_float(uB.z & 0xffff0000u) * wB;
        aB[6] += __uint_as_float(uB.w << 16) * wB;
        aB[7] += __uint_as_float(uB.w & 0xffff0000u) * wB;
    }
    float a[8];
#pragma unroll
    for (int i = 0; i < 8; ++i) {
        a[i] = aA[i] + aB[i];
        a[i] += __shfl_xor(a[i], 16);
        a[i] += __shfl_xor(a[i], 32);
    }
    if (eg == 0) {
        float* o = out + (size_t)row * HDIM + sl * 8;
        *(float4*)o       = make_float4(a[0], a[1], a[2], a[3]);
        *(float4*)(o + 4) = make_float4(a[4], a[5], a[6], a[7]);
    }
}

extern "C" void kernel_launch(void* const* d_in, const int* in_sizes, int n_in,
                              void* d_out, int out_size, void* d_ws, size_t ws_size,
                              hipStream_t stream)
{
    const float* x  = (const float*)d_in[0];
    const int*   ei = (const int*)d_in[1];
    const float* ew = (const float*)d_in[2];
    const float* Wq = (const float*)d_in[3];
    const float* bq = (const float*)d_in[4];
    const float* Wk = (const float*)d_in[5];
    const float* bk = (const float*)d_in[6];
    const float* Wv = (const float*)d_in[7];
    const float* bv = (const float*)d_in[8];
    float* out = (float*)d_out;

    float* ws = (float*)d_ws;
    float* Q       = ws;                                  // N*H fp32
    unsigned short* Kb = (unsigned short*)(Q + (size_t)N_NODES * HDIM);  // N*H bf16
    unsigned short* Vb = Kb + (size_t)N_NODES * HDIM;     // N*H bf16
    int*   counts  = (int*)(Vb + (size_t)N_NODES * HDIM); // N
    int*   offs    = counts + N_NODES;                    // N
    int*   cursor  = offs + N_NODES;                      // N
    int*   aux     = cursor + N_NODES;                    // SCAN_BLOCKS (256 slots)
    uint2* erec    = (uint2*)(aux + 256);                 // E records (col, ew/en/p)
    float* blockmax= (float*)(erec + E_EDGES);            // ROW_BLOCKS
    float* blocksum= blockmax + ROW_BLOCKS;               // EDGE_BLOCKS
    float* gmax    = blocksum + EDGE_BLOCKS;              // 1
    float* gsum    = gmax + 1;                            // 1

    hipMemsetAsync(counts, 0, N_NODES * sizeof(int), stream);

    qkv_mfma_kernel<<<QKV_BLOCKS, 256, 0, stream>>>(
        x, Wq, bq, Wk, bk, Wv, bv, Q, Kb, Vb);
    hist_kernel<<<EDGE_BLOCKS, 256, 0, stream>>>(ei, counts);
    scan_partial_kernel<<<SCAN_BLOCKS, 256, 0, stream>>>(counts, offs, aux);
    scan_aux_kernel<<<1, 256, 0, stream>>>(aux);
    scan_add_kernel<<<SCAN_BLOCKS, 256, 0, stream>>>(offs, aux, cursor);
    bin_kernel<<<EDGE_BLOCKS, 256, 0, stream>>>(ei, ew, cursor, erec);
    energy_kernel<<<ROW_BLOCKS, 256, 0, stream>>>(Q, Kb, offs, counts, erec, blockmax);
    reduce_max_kernel<<<1, 256, 0, stream>>>(blockmax, ROW_BLOCKS, gmax);
    expsum_kernel<<<EDGE_BLOCKS, 256, 0, stream>>>(erec, gmax, blocksum);
    reduce_sum_kernel<<<1, 256, 0, stream>>>(blocksum, EDGE_BLOCKS, gsum);
    accum_kernel<<<ROW_BLOCKS, 256, 0, stream>>>(Vb, offs, counts, erec, gsum, out);
}

// Round 15
// 190.428 us; speedup vs baseline: 1.3834x; 1.3834x over previous
//
#include <hip/hip_runtime.h>
#include <hip/hip_bf16.h>

#define N_NODES 50000
#define E_EDGES 600000
#define HDIM    128

#define QKV_BLOCKS  ((N_NODES + 63) / 64)     // 782 (64 rows/block, x3 mats grid.y)
#define EDGE_BLOCKS ((E_EDGES + 255) / 256)   // 2344
#define SCAN_BLOCKS ((N_NODES + 255) / 256)   // 196
#define ROW_BLOCKS  (N_NODES / 4)             // 12500 (4 waves/block, 1 wave/row)

typedef float f32x4  __attribute__((ext_vector_type(4)));
typedef short short8 __attribute__((ext_vector_type(8)));

__device__ __forceinline__ unsigned short f2bf(float f) {
    __hip_bfloat16 h = __float2bfloat16(f);
    return *reinterpret_cast<unsigned short*>(&h);
}

// ---- Phase 1 (MFMA): Y = x W^T + b for W in {Wq,Wk,Wv} (blockIdx.y picks mat)
// Split precision: x = xh + xl, W = Wh + Wl (bf16); Y = xh*Wh + xl*Wh + xh*Wl.
// NOTE: fusing the 3 mats into one block was tried (r12-r14) and always loses:
// 3x64 VGPR of B-frags -> either 8% occupancy (unrolled) or scratch spills
// (capped). grid.y=3 with 3x L2-resident x refetch is the measured optimum.
__global__ __launch_bounds__(256) void qkv_mfma_kernel(
    const float* __restrict__ x,
    const float* __restrict__ Wq, const float* __restrict__ bq,
    const float* __restrict__ Wk, const float* __restrict__ bk,
    const float* __restrict__ Wv, const float* __restrict__ bv,
    float* __restrict__ Q, unsigned short* __restrict__ Kb,
    unsigned short* __restrict__ Vb)
{
    __shared__ __align__(16) unsigned short Ah[64 * HDIM];  // 16 KB
    __shared__ __align__(16) unsigned short Al[64 * HDIM];  // 16 KB
    const int r0  = blockIdx.x * 64;
    const int mat = blockIdx.y;          // 0=Q 1=K 2=V

    // ---- stage x rows 64x128 as bf16 hi/lo, swizzled ----
    for (int t = threadIdx.x; t < 2048; t += 256) {
        const int r  = t >> 5;           // 0..63
        const int k4 = t & 31;           // float4 index 0..31
        int gr = r0 + r; if (gr >= N_NODES) gr = N_NODES - 1;
        const float4 xv = *(const float4*)&x[(size_t)gr * HDIM + k4 * 4];
        const unsigned ux = __float_as_uint(xv.x), uy = __float_as_uint(xv.y);
        const unsigned uz = __float_as_uint(xv.z), uw = __float_as_uint(xv.w);
        ushort4 hv, lv;
        hv.x = (unsigned short)(ux >> 16); hv.y = (unsigned short)(uy >> 16);
        hv.z = (unsigned short)(uz >> 16); hv.w = (unsigned short)(uw >> 16);
        lv.x = f2bf(xv.x - __uint_as_float(ux & 0xffff0000u));
        lv.y = f2bf(xv.y - __uint_as_float(uy & 0xffff0000u));
        lv.z = f2bf(xv.z - __uint_as_float(uz & 0xffff0000u));
        lv.w = f2bf(xv.w - __uint_as_float(uw & 0xffff0000u));
        const int byte = (r << 8) + (k4 << 3);
        const int swz  = byte ^ ((r & 7) << 4);
        *(ushort4*)((char*)Ah + swz) = hv;
        *(ushort4*)((char*)Al + swz) = lv;
    }

    const int lane = threadIdx.x & 63;
    const int w    = threadIdx.x >> 6;   // wave 0..3
    const int lrow = lane & 15;
    const int lgrp = lane >> 4;
    const int nb   = w * 32;             // wave's col base within mat

    const float* Wm = (mat == 0) ? Wq : (mat == 1) ? Wk : Wv;
    const float* bm = (mat == 0) ? bq : (mat == 1) ? bk : bv;

    // ---- B fragments: hi/lo, 2 strips x 4 k-steps ----
    short8 Bh[2][4], Bl[2][4];
#pragma unroll
    for (int st = 0; st < 2; ++st) {
        const int col = nb + st * 16 + lrow;
#pragma unroll
        for (int ks = 0; ks < 4; ++ks) {
            const int k0 = ks * 32 + lgrp * 8;
            const float* p = Wm + (size_t)col * HDIM + k0;
            const float4 a = *(const float4*)p;
            const float4 b = *(const float4*)(p + 4);
            const float f[8] = {a.x, a.y, a.z, a.w, b.x, b.y, b.z, b.w};
            short8 h, l;
#pragma unroll
            for (int j = 0; j < 8; ++j) {
                const unsigned u = __float_as_uint(f[j]);
                h[j] = (short)(u >> 16);
                l[j] = (short)f2bf(f[j] - __uint_as_float(u & 0xffff0000u));
            }
            Bh[st][ks] = h; Bl[st][ks] = l;
        }
    }
    const float bias0 = bm[nb + lrow];
    const float bias1 = bm[nb + 16 + lrow];

    __syncthreads();

    // ---- compute: 4 M-subtiles of 16 rows ----
#pragma unroll
    for (int s = 0; s < 4; ++s) {
        f32x4 acc0 = {0.f, 0.f, 0.f, 0.f};
        f32x4 acc1 = {0.f, 0.f, 0.f, 0.f};
        const int row = s * 16 + lrow;
#pragma unroll
        for (int ks = 0; ks < 4; ++ks) {
            const int byte = (row << 8) + ((ks * 32 + lgrp * 8) << 1);
            const int swz  = byte ^ ((row & 7) << 4);
            const short8 ah = *(const short8*)((const char*)Ah + swz);
            const short8 al = *(const short8*)((const char*)Al + swz);
            acc0 = __builtin_amdgcn_mfma_f32_16x16x32_bf16(ah, Bh[0][ks], acc0, 0, 0, 0);
            acc0 = __builtin_amdgcn_mfma_f32_16x16x32_bf16(al, Bh[0][ks], acc0, 0, 0, 0);
            acc0 = __builtin_amdgcn_mfma_f32_16x16x32_bf16(ah, Bl[0][ks], acc0, 0, 0, 0);
            acc1 = __builtin_amdgcn_mfma_f32_16x16x32_bf16(ah, Bh[1][ks], acc1, 0, 0, 0);
            acc1 = __builtin_amdgcn_mfma_f32_16x16x32_bf16(al, Bh[1][ks], acc1, 0, 0, 0);
            acc1 = __builtin_amdgcn_mfma_f32_16x16x32_bf16(ah, Bl[1][ks], acc1, 0, 0, 0);
        }
        const int orow0 = r0 + s * 16 + lgrp * 4;
        if (mat == 0) {
#pragma unroll
            for (int i = 0; i < 4; ++i) {
                const int row_o = orow0 + i;
                if (row_o < N_NODES) {
                    Q[(size_t)row_o * HDIM + nb + lrow]      = acc0[i] + bias0;
                    Q[(size_t)row_o * HDIM + nb + 16 + lrow] = acc1[i] + bias1;
                }
            }
        } else {
            unsigned short* dst = (mat == 1) ? Kb : Vb;
#pragma unroll
            for (int i = 0; i < 4; ++i) {
                const int row_o = orow0 + i;
                if (row_o < N_NODES) {
                    dst[(size_t)row_o * HDIM + nb + lrow]      = f2bf(acc0[i] + bias0);
                    dst[(size_t)row_o * HDIM + nb + 16 + lrow] = f2bf(acc1[i] + bias1);
                }
            }
        }
    }
}

// ---- Phase 2a: histogram of destination rows ----
__global__ __launch_bounds__(256) void hist_kernel(
    const int* __restrict__ ei, int* __restrict__ counts)
{
    const int e = blockIdx.x * 256 + threadIdx.x;
    if (e < E_EDGES) atomicAdd(&counts[ei[e]], 1);
}

// ---- Phase 2b: exclusive prefix scan (3 small kernels) ----
__global__ __launch_bounds__(256) void scan_partial_kernel(
    const int* __restrict__ counts, int* __restrict__ offs, int* __restrict__ aux)
{
    __shared__ int s[256];
    const int i = blockIdx.x * 256 + threadIdx.x;
    const int v = (i < N_NODES) ? counts[i] : 0;
    s[threadIdx.x] = v;
    __syncthreads();
    for (int d = 1; d < 256; d <<= 1) {
        int t = (threadIdx.x >= d) ? s[threadIdx.x - d] : 0;
        __syncthreads();
        s[threadIdx.x] += t;
        __syncthreads();
    }
    if (i < N_NODES) offs[i] = s[threadIdx.x] - v;   // exclusive within block
    if (threadIdx.x == 255) aux[blockIdx.x] = s[255];
}

__global__ __launch_bounds__(256) void scan_aux_kernel(int* __restrict__ aux)
{
    __shared__ int s[256];
    const int i = threadIdx.x;
    const int v = (i < SCAN_BLOCKS) ? aux[i] : 0;
    s[i] = v;
    __syncthreads();
    for (int d = 1; d < 256; d <<= 1) {
        int t = (i >= d) ? s[i - d] : 0;
        __syncthreads();
        s[i] += t;
        __syncthreads();
    }
    if (i < SCAN_BLOCKS) aux[i] = s[i] - v;          // exclusive
}

__global__ __launch_bounds__(256) void scan_add_kernel(
    int* __restrict__ offs, const int* __restrict__ aux, int* __restrict__ cursor)
{
    const int i = blockIdx.x * 256 + threadIdx.x;
    if (i < N_NODES) {
        const int o = offs[i] + aux[blockIdx.x];
        offs[i] = o;
        cursor[i] = o;
    }
}

// ---- Phase 2c: bin edges by destination row; ONE 8B record per edge ----
__global__ __launch_bounds__(256) void bin_kernel(
    const int* __restrict__ ei, const float* __restrict__ ew,
    int* __restrict__ cursor, uint2* __restrict__ erec)
{
    const int e = blockIdx.x * 256 + threadIdx.x;
    if (e >= E_EDGES) return;
    const int row = ei[e];
    const int pos = atomicAdd(&cursor[row], 1);
    erec[pos] = make_uint2((unsigned)ei[E_EDGES + e], __float_as_uint(ew[e]));
}

// ---- Phase 3: energy; 8 edges/wave in flight; per-block max array ----
__global__ __launch_bounds__(256) void energy_kernel(
    const float* __restrict__ Q, const unsigned short* __restrict__ Kb,
    const int* __restrict__ offs, const int* __restrict__ counts,
    uint2* __restrict__ erec, float* __restrict__ blockmax)
{
    const int row  = (blockIdx.x * 256 + threadIdx.x) >> 6;
    const int lane = threadIdx.x & 63;
    const int eg   = lane >> 4;     // edge group 0..3
    const int sl   = lane & 15;     // sub-lane in group
    const int start = offs[row], len = counts[row];
    const float4 q0 = *(const float4*)&Q[(size_t)row * HDIM + sl * 8];
    const float4 q1 = *(const float4*)&Q[(size_t)row * HDIM + sl * 8 + 4];
    const uint4* kb128 = (const uint4*)Kb;   // one row = 16 uint4
    const float inv_scale = 0.08838834764831845f;  // 1/sqrt(128)
    float lmax = -3.4e38f;
    for (int j0 = 0; j0 < len; j0 += 8) {
        const int  jA = j0 + eg,      jB = j0 + 4 + eg;
        const bool vA = jA < len,     vB = jB < len;
        const int  eA = start + (vA ? jA : 0);
        const int  eB = start + (vB ? jB : 0);
        const uint2 rA = erec[eA];
        const uint2 rB = erec[eB];
        const uint4 uA = kb128[(size_t)rA.x * 16 + sl];
        const uint4 uB = kb128[(size_t)rB.x * 16 + sl];
        float dA = q0.x * __uint_as_float(uA.x << 16)
                 + q0.y * __uint_as_float(uA.x & 0xffff0000u)
                 + q0.z * __uint_as_float(uA.y << 16)
                 + q0.w * __uint_as_float(uA.y & 0xffff0000u)
                 + q1.x * __uint_as_float(uA.z << 16)
                 + q1.y * __uint_as_float(uA.z & 0xffff0000u)
                 + q1.z * __uint_as_float(uA.w << 16)
                 + q1.w * __uint_as_float(uA.w & 0xffff0000u);
        float dB = q0.x * __uint_as_float(uB.x << 16)
                 + q0.y * __uint_as_float(uB.x & 0xffff0000u)
                 + q0.z * __uint_as_float(uB.y << 16)
                 + q0.w * __uint_as_float(uB.y & 0xffff0000u)
                 + q1.x * __uint_as_float(uB.z << 16)
                 + q1.y * __uint_as_float(uB.z & 0xffff0000u)
                 + q1.z * __uint_as_float(uB.w << 16)
                 + q1.w * __uint_as_float(uB.w & 0xffff0000u);
#pragma unroll
        for (int m = 8; m >= 1; m >>= 1) {
            dA += __shfl_xor(dA, m);
            dB += __shfl_xor(dB, m);
        }
        const float enA = dA * inv_scale * __uint_as_float(rA.y);
        const float enB = dB * inv_scale * __uint_as_float(rB.y);
        if (vA) {
            lmax = fmaxf(lmax, enA);
            if (sl == 0) ((float*)erec)[2 * eA + 1] = enA;
        }
        if (vB) {
            lmax = fmaxf(lmax, enB);
            if (sl == 0) ((float*)erec)[2 * eB + 1] = enB;
        }
    }
#pragma unroll
    for (int m = 32; m >= 1; m >>= 1) lmax = fmaxf(lmax, __shfl_xor(lmax, m));
    __shared__ float sm[4];
    if (lane == 0) sm[threadIdx.x >> 6] = lmax;
    __syncthreads();
    if (threadIdx.x == 0)
        blockmax[blockIdx.x] = fmaxf(fmaxf(sm[0], sm[1]), fmaxf(sm[2], sm[3]));
}

__global__ __launch_bounds__(256) void reduce_max_kernel(
    const float* __restrict__ bm, int n, float* __restrict__ gmax)
{
    float m = -3.4e38f;
    for (int i = threadIdx.x; i < n; i += 256) m = fmaxf(m, bm[i]);
#pragma unroll
    for (int s = 32; s >= 1; s >>= 1) m = fmaxf(m, __shfl_xor(m, s));
    __shared__ float sm[4];
    if ((threadIdx.x & 63) == 0) sm[threadIdx.x >> 6] = m;
    __syncthreads();
    if (threadIdx.x == 0) *gmax = fmaxf(fmaxf(sm[0], sm[1]), fmaxf(sm[2], sm[3]));
}

// ---- Phase 4: erec.y = exp(erec.y - max); per-block sum array ----
__global__ __launch_bounds__(256) void expsum_kernel(
    uint2* __restrict__ erec, const float* __restrict__ gmax,
    float* __restrict__ blocksum)
{
    const float m = *gmax;
    const int e = blockIdx.x * 256 + threadIdx.x;
    float p = 0.f;
    if (e < E_EDGES) {
        const uint2 r = erec[e];
        p = __expf(__uint_as_float(r.y) - m);
        erec[e] = make_uint2(r.x, __float_as_uint(p));
    }
#pragma unroll
    for (int s = 32; s >= 1; s >>= 1) p += __shfl_xor(p, s);
    __shared__ float sm[4];
    if ((threadIdx.x & 63) == 0) sm[threadIdx.x >> 6] = p;
    __syncthreads();
    if (threadIdx.x == 0) blocksum[blockIdx.x] = sm[0] + sm[1] + sm[2] + sm[3];
}

__global__ __launch_bounds__(256) void reduce_sum_kernel(
    const float* __restrict__ bs, int n, float* __restrict__ gsum)
{
    float v = 0.f;
    for (int i = threadIdx.x; i < n; i += 256) v += bs[i];
#pragma unroll
    for (int s = 32; s >= 1; s >>= 1) v += __shfl_xor(v, s);
    __shared__ float sm[4];
    if ((threadIdx.x & 63) == 0) sm[threadIdx.x >> 6] = v;
    __syncthreads();
    if (threadIdx.x == 0) *gsum = sm[0] + sm[1] + sm[2] + sm[3];
}

// ---- Phase 5: out[row] = sum_j V[col_j] * p_j / gsum; 8 edges in flight ----
__global__ __launch_bounds__(256) void accum_kernel(
    const unsigned short* __restrict__ Vb,
    const int* __restrict__ offs, const int* __restrict__ counts,
    const uint2* __restrict__ erec, const float* __restrict__ gsum,
    float* __restrict__ out)
{
    const int row  = (blockIdx.x * 256 + threadIdx.x) >> 6;
    const int lane = threadIdx.x & 63;
    const int eg   = lane >> 4;     // edge group 0..3
    const int sl   = lane & 15;     // sub-lane: dims sl*8..sl*8+7
    const float inv = 1.0f / *gsum;
    const int start = offs[row], len = counts[row];
    const uint4* vb128 = (const uint4*)Vb;   // one row = 16 uint4
    float aA[8] = {0.f, 0.f, 0.f, 0.f, 0.f, 0.f, 0.f, 0.f};
    float aB[8] = {0.f, 0.f, 0.f, 0.f, 0.f, 0.f, 0.f, 0.f};
    for (int j0 = 0; j0 < len; j0 += 8) {
        const int  jA = j0 + eg,      jB = j0 + 4 + eg;
        const bool vA = jA < len,     vB = jB < len;
        const int  eA = start + (vA ? jA : 0);
        const int  eB = start + (vB ? jB : 0);
        const uint2 rA = erec[eA];
        const uint2 rB = erec[eB];
        const float wA = vA ? __uint_as_float(rA.y) * inv : 0.f;
        const float wB = vB ? __uint_as_float(rB.y) * inv : 0.f;
        const uint4 uA = vb128[(size_t)rA.x * 16 + sl];
        const uint4 uB = vb128[(size_t)rB.x * 16 + sl];
        aA[0] += __uint_as_float(uA.x << 16) * wA;
        aA[1] += __uint_as_float(uA.x & 0xffff0000u) * wA;
        aA[2] += __uint_as_float(uA.y << 16) * wA;
        aA[3] += __uint_as_float(uA.y & 0xffff0000u) * wA;
        aA[4] += __uint_as_float(uA.z << 16) * wA;
        aA[5] += __uint_as_float(uA.z & 0xffff0000u) * wA;
        aA[6] += __uint_as_float(uA.w << 16) * wA;
        aA[7] += __uint_as_float(uA.w & 0xffff0000u) * wA;
        aB[0] += __uint_as_float(uB.x << 16) * wB;
        aB[1] += __uint_as_float(uB.x & 0xffff0000u) * wB;
        aB[2] += __uint_as_float(uB.y << 16) * wB;
        aB[3] += __uint_as_float(uB.y & 0xffff0000u) * wB;
        aB[4] += __uint_as_float(uB.z << 16) * wB;
        aB[5] += __uint_as_float(uB.z & 0xffff0000u) * wB;
        aB[6] += __uint_as_float(uB.w << 16) * wB;
        aB[7] += __uint_as_float(uB.w & 0xffff0000u) * wB;
    }
    float a[8];
#pragma unroll
    for (int i = 0; i < 8; ++i) {
        a[i] = aA[i] + aB[i];
        a[i] += __shfl_xor(a[i], 16);
        a[i] += __shfl_xor(a[i], 32);
    }
    if (eg == 0) {
        float* o = out + (size_t)row * HDIM + sl * 8;
        *(float4*)o       = make_float4(a[0], a[1], a[2], a[3]);
        *(float4*)(o + 4) = make_float4(a[4], a[5], a[6], a[7]);
    }
}

extern "C" void kernel_launch(void* const* d_in, const int* in_sizes, int n_in,
                              void* d_out, int out_size, void* d_ws, size_t ws_size,
                              hipStream_t stream)
{
    const float* x  = (const float*)d_in[0];
    const int*   ei = (const int*)d_in[1];
    const float* ew = (const float*)d_in[2];
    const float* Wq = (const float*)d_in[3];
    const float* bq = (const float*)d_in[4];
    const float* Wk = (const float*)d_in[5];
    const float* bk = (const float*)d_in[6];
    const float* Wv = (const float*)d_in[7];
    const float* bv = (const float*)d_in[8];
    float* out = (float*)d_out;

    float* ws = (float*)d_ws;
    float* Q       = ws;                                  // N*H fp32
    unsigned short* Kb = (unsigned short*)(Q + (size_t)N_NODES * HDIM);  // N*H bf16
    unsigned short* Vb = Kb + (size_t)N_NODES * HDIM;     // N*H bf16
    int*   counts  = (int*)(Vb + (size_t)N_NODES * HDIM); // N
    int*   offs    = counts + N_NODES;                    // N
    int*   cursor  = offs + N_NODES;                      // N
    int*   aux     = cursor + N_NODES;                    // SCAN_BLOCKS (256 slots)
    uint2* erec    = (uint2*)(aux + 256);                 // E records (col, ew/en/p)
    float* blockmax= (float*)(erec + E_EDGES);            // ROW_BLOCKS
    float* blocksum= blockmax + ROW_BLOCKS;               // EDGE_BLOCKS
    float* gmax    = blocksum + EDGE_BLOCKS;              // 1
    float* gsum    = gmax + 1;                            // 1

    hipMemsetAsync(counts, 0, N_NODES * sizeof(int), stream);

    qkv_mfma_kernel<<<dim3(QKV_BLOCKS, 3), 256, 0, stream>>>(
        x, Wq, bq, Wk, bk, Wv, bv, Q, Kb, Vb);
    hist_kernel<<<EDGE_BLOCKS, 256, 0, stream>>>(ei, counts);
    scan_partial_kernel<<<SCAN_BLOCKS, 256, 0, stream>>>(counts, offs, aux);
    scan_aux_kernel<<<1, 256, 0, stream>>>(aux);
    scan_add_kernel<<<SCAN_BLOCKS, 256, 0, stream>>>(offs, aux, cursor);
    bin_kernel<<<EDGE_BLOCKS, 256, 0, stream>>>(ei, ew, cursor, erec);
    energy_kernel<<<ROW_BLOCKS, 256, 0, stream>>>(Q, Kb, offs, counts, erec, blockmax);
    reduce_max_kernel<<<1, 256, 0, stream>>>(blockmax, ROW_BLOCKS, gmax);
    expsum_kernel<<<EDGE_BLOCKS, 256, 0, stream>>>(erec, gmax, blocksum);
    reduce_sum_kernel<<<1, 256, 0, stream>>>(blocksum, EDGE_BLOCKS, gsum);
    accum_kernel<<<ROW_BLOCKS, 256, 0, stream>>>(Vb, offs, counts, erec, gsum, out);
}